// Round 1
// baseline (14590.262 us; speedup 1.0000x reference)
//
#include <hip/hip_runtime.h>
#include <hip/hip_bf16.h>

#define B_    4096
#define T_    365
#define F_    16
#define H_    256
#define G4    1024            // 4*H
#define BB    16              // batch rows per block
#define DEPTH (H_ + F_)       // 272 = hidden + input features

// ---------------------------------------------------------------------------
// prep: build transposed/interleaved weight table in ws:
//   wsT2[k][u][g] = W[g*256+u][k]   (k<256 -> W_hh, k>=256 -> W_ih col k-256)
// so a thread's 4 gate-weights for depth-index k are one float4, coalesced
// across lanes u. Also biasSum = b_ih + b_hh.
// ---------------------------------------------------------------------------
__global__ __launch_bounds__(256) void prep_kernel(
    const float* __restrict__ W_ih, const float* __restrict__ W_hh,
    const float* __restrict__ b_ih, const float* __restrict__ b_hh,
    float* __restrict__ wsT2, float* __restrict__ biasSum) {
  const int k = blockIdx.x;    // 0..DEPTH-1
  const int u = threadIdx.x;   // 0..255
  float4 v;
  if (k < H_) {
    v.x = W_hh[(0 * H_ + u) * H_ + k];
    v.y = W_hh[(1 * H_ + u) * H_ + k];
    v.z = W_hh[(2 * H_ + u) * H_ + k];
    v.w = W_hh[(3 * H_ + u) * H_ + k];
  } else {
    const int f = k - H_;
    v.x = W_ih[(0 * H_ + u) * F_ + f];
    v.y = W_ih[(1 * H_ + u) * F_ + f];
    v.z = W_ih[(2 * H_ + u) * F_ + f];
    v.w = W_ih[(3 * H_ + u) * F_ + f];
  }
  reinterpret_cast<float4*>(wsT2)[k * H_ + u] = v;
  if (k < 4) {
    const int j = k * H_ + u;
    biasSum[j] = b_ih[j] + b_hh[j];
  }
}

__device__ __forceinline__ float sigmoidf_(float x) {
  return 1.0f / (1.0f + __expf(-x));
}
// overflow-safe tanh via exp(-2|x|)
__device__ __forceinline__ float tanh_s(float x) {
  const float ax = fabsf(x);
  const float t  = __expf(-2.0f * ax);
  const float r  = (1.0f - t) / (1.0f + t);
  return x < 0.0f ? -r : r;
}

// ---------------------------------------------------------------------------
// Persistent LSTM: 256 blocks x 256 threads. Block owns BB=16 batch rows for
// all 365 steps (no grid sync). Thread u owns hidden unit u: computes gate
// rows {u, 256+u, 512+u, 768+u} for all 16 rows; c stays in registers.
// h kept transposed in LDS vT[k][row]; lanes broadcast-read it (uniform addr).
// ---------------------------------------------------------------------------
__global__ __launch_bounds__(256, 1) void lstm_kernel(
    const float* __restrict__ w, const float* __restrict__ wsT2,
    const float* __restrict__ biasSum, const float* __restrict__ W_out,
    const float* __restrict__ b_out, float* __restrict__ out) {
  __shared__ float vT[DEPTH][BB];      // [depth-k][batch-row]; rows 256+ = x_t
  __shared__ float red[2][H_][BB];     // epilogue reduction buffer

  const int tid = threadIdx.x;
  const int u   = tid;                 // hidden unit owned by this thread
  const int b0  = blockIdx.x * BB;
  const int xrow = tid >> 4, xf = tid & 15;   // x-staging assignment

  float bias[4];
#pragma unroll
  for (int g = 0; g < 4; ++g) bias[g] = biasSum[g * H_ + u];

  float c_[BB], hreg[BB];
#pragma unroll
  for (int r = 0; r < BB; ++r) { c_[r] = 0.0f; hreg[r] = 0.0f; vT[u][r] = 0.0f; }

  // stage x for t=0 (rows 256..271 of vT)
  vT[H_ + xf][xrow] = w[(size_t)(b0 + xrow) * (T_ * F_) + 0 * F_ + xf];
  __syncthreads();

  const float4* __restrict__ wp = reinterpret_cast<const float4*>(wsT2) + u;

  for (int t = 0; t < T_; ++t) {
    float acc0[BB], acc1[BB], acc2[BB], acc3[BB];
#pragma unroll
    for (int r = 0; r < BB; ++r) acc0[r] = acc1[r] = acc2[r] = acc3[r] = 0.0f;

#pragma unroll 2
    for (int k = 0; k < DEPTH; ++k) {
      const float4 wv = wp[(size_t)k * H_];          // coalesced, L2-resident
      const float4* hp = reinterpret_cast<const float4*>(&vT[k][0]);
      float hv[BB];
      *reinterpret_cast<float4*>(&hv[0])  = hp[0];   // uniform addr -> LDS bcast
      *reinterpret_cast<float4*>(&hv[4])  = hp[1];
      *reinterpret_cast<float4*>(&hv[8])  = hp[2];
      *reinterpret_cast<float4*>(&hv[12]) = hp[3];
#pragma unroll
      for (int r = 0; r < BB; ++r) {
        acc0[r] = fmaf(wv.x, hv[r], acc0[r]);
        acc1[r] = fmaf(wv.y, hv[r], acc1[r]);
        acc2[r] = fmaf(wv.z, hv[r], acc2[r]);
        acc3[r] = fmaf(wv.w, hv[r], acc3[r]);
      }
    }
    __syncthreads();   // all reads of vT done before overwriting

    // activations + state update (thread-local: i,f,g,o all belong to unit u)
#pragma unroll
    for (int r = 0; r < BB; ++r) {
      const float ig = sigmoidf_(acc0[r] + bias[0]);
      const float fg = sigmoidf_(acc1[r] + bias[1]);
      const float gg = tanh_s  (acc2[r] + bias[2]);
      const float og = sigmoidf_(acc3[r] + bias[3]);
      const float cn = fg * c_[r] + ig * gg;
      c_[r] = cn;
      hreg[r] = og * tanh_s(cn);
    }
    // write h back transposed (4x b128)
#pragma unroll
    for (int q = 0; q < 4; ++q) {
      float4 v4 = make_float4(hreg[4 * q + 0], hreg[4 * q + 1],
                              hreg[4 * q + 2], hreg[4 * q + 3]);
      *reinterpret_cast<float4*>(&vT[u][4 * q]) = v4;
    }
    // stage x for t+1
    if (t + 1 < T_) {
      vT[H_ + xf][xrow] =
          w[(size_t)(b0 + xrow) * (T_ * F_) + (size_t)(t + 1) * F_ + xf];
    }
    __syncthreads();
  }

  // ---- epilogue ----
  // h output: out[8192 + b*256 + u]
#pragma unroll
  for (int r = 0; r < BB; ++r) {
    out[8192 + (size_t)(b0 + r) * H_ + u] = hreg[r];
  }
  // tz0 = ELU(h) @ W_out^T + b_out
  const float w0 = W_out[u], w1 = W_out[H_ + u];
#pragma unroll
  for (int r = 0; r < BB; ++r) {
    const float e = hreg[r] > 0.0f ? hreg[r] : (__expf(hreg[r]) - 1.0f);
    red[0][u][r] = e * w0;
    red[1][u][r] = e * w1;
  }
  __syncthreads();
  if (tid < 32) {
    const int r = tid >> 1, o = tid & 1;
    float s = b_out[o];
#pragma unroll 8
    for (int uu = 0; uu < H_; ++uu) s += red[o][uu][r];
    out[(size_t)o * B_ + b0 + r] = s;
  }
}

extern "C" void kernel_launch(void* const* d_in, const int* in_sizes, int n_in,
                              void* d_out, int out_size, void* d_ws, size_t ws_size,
                              hipStream_t stream) {
  const float* w     = (const float*)d_in[0];
  const float* W_ih  = (const float*)d_in[1];
  const float* W_hh  = (const float*)d_in[2];
  const float* b_ih  = (const float*)d_in[3];
  const float* b_hh  = (const float*)d_in[4];
  const float* W_out = (const float*)d_in[5];
  const float* b_out = (const float*)d_in[6];
  float* out = (float*)d_out;

  float* wsT2    = (float*)d_ws;             // DEPTH*1024 floats (~1.09 MB)
  float* biasSum = wsT2 + (size_t)DEPTH * G4;  // 1024 floats

  hipLaunchKernelGGL(prep_kernel, dim3(DEPTH), dim3(256), 0, stream,
                     W_ih, W_hh, b_ih, b_hh, wsT2, biasSum);
  hipLaunchKernelGGL(lstm_kernel, dim3(B_ / BB), dim3(256), 0, stream,
                     w, wsT2, biasSum, W_out, b_out, out);
}